// Round 8
// baseline (183.558 us; speedup 1.0000x reference)
//
#include <hip/hip_runtime.h>

// Fused LSTM(H=128) + 3-layer MLP head, fp16 MFMA (16x16x32), fp32 state.
// B=8192 rows, T=30 steps. 256 blocks x 512 threads (8 waves), 32 rows/block.
// ROUND 8 (on r7's 90.5us): async-stage the gather (T14 issue-early/
// write-late). r7 emitted global_load -> waitcnt -> ds_write at the TOP of
// phase A, stalling the 4 gather-waves ~200-500cy (L2-hit, stride-120B
// feature reads) before any z-MFMA issued. Now: phase A(i) issues loads for
// step i+2 into regs (no wait); phase B(i) ds_writes them to xp[i&1] (whose
// reads completed at the A->B barrier; consumed at A(i+2), 2 barriers later).
// vmcnt resolves ~a full phase after issue -> latency hidden. Tail: issue in
// TA(s), write in TD(s) (s<=27; j7 always 0 there). Bit-identical arithmetic.
// Prior lessons kept: 2 waves/SIMD is the reg ceiling (r4/r5 spills); fp16
// single precision (r7, absmax unchanged 0.001953125); warm pipeline with
// MLP1 fused on z's h-panel reads, 2 barriers/warm step (r6); tail p-inject
// via VALU acc += p*Wi[7][col] (r7).
// - Wave w owns output cols [16w,16w+16); 2 M-tiles (rows 0-15,16-31).
// - x-frag: K slots 0..7 = 8 features, 8..31 zero.
// - 16x16x32 layouts: A/B: row|col=lane&15, k=(lane>>4)*8+j; C/D: col=lane&15,
//   row=(lane>>4)*4+reg (m89-verified, dtype-independent).
// - A-panels [16 rows][40 halfs] (32 data + 8 pad): 16B-aligned b128 reads.
// - fp32: accumulators, c-state, gates, o2, head, feedback p.

#define T_STEPS 30
#define WARM_N  24

typedef _Float16 h8 __attribute__((ext_vector_type(8)));     // 8 fp16 = 4 VGPRs
typedef __attribute__((ext_vector_type(4))) float float4v;   // MFMA 16x16 C/D

struct FeatPtrs { const float* f[7]; };

#if __has_builtin(__builtin_amdgcn_rcpf)
#define RCP(x) __builtin_amdgcn_rcpf(x)
#else
#define RCP(x) (1.0f/(x))
#endif

__device__ __forceinline__ float sigm(float x){ return RCP(1.0f + __expf(-x)); }
__device__ __forceinline__ float tanh_(float x){ return 1.0f - 2.0f*RCP(1.0f + __expf(2.0f*x)); }

// ---------------- weight pack kernel ----------------
// 224 frags of 512 fp16 (1 KB each), frag elem (lane,j):
//   col16 = lane&15, kk = (lane>>4)*8 + j  (K=32 per fragment)
// frags 0..159 : z-weights [wt 0..7][g 0..3][ks 0..4]
//   ks=0: x-frag: kk<8 -> Wi[kk][col], kk>=8 -> 0
//   ks 1..4: Wh[(ks-1)*32+kk][col];  col = g*128+wt*16+col16
// frags 160..191: W1 [wt][ks 0..3]: W1[ks*32+kk][wt*16+col16]
// frags 192..223: W2 same layout.
__global__ void pack_weights(const float* __restrict__ Wi, const float* __restrict__ Wh,
                             const float* __restrict__ W1, const float* __restrict__ W2,
                             _Float16* __restrict__ ws)
{
  int idx = blockIdx.x * 256 + threadIdx.x;
  if (idx >= 224 * 512) return;
  int f    = idx >> 9;
  int r    = idx & 511;
  int lane = r >> 3, j = r & 7;
  int kk   = ((lane >> 4) << 3) + j;     // 0..31
  int c16  = lane & 15;
  float v = 0.0f;
  if (f < 160){
    int wt = f / 20, rem = f % 20, g = rem / 5, ks = rem % 5;
    int col = g * 128 + wt * 16 + c16;
    if (ks == 0) v = (kk < 8) ? Wi[kk * 512 + col] : 0.0f;
    else         v = Wh[((ks - 1) * 32 + kk) * 512 + col];
  } else {
    int f2 = f - 160;                    // 0..63
    const float* W = (f2 < 32) ? W1 : W2;
    int f3 = f2 & 31;
    int wt = f3 >> 2, ks = f3 & 3;
    v = W[(ks * 32 + kk) * 128 + wt * 16 + c16];
  }
  ws[idx] = (_Float16)v;
}

// ---------------- head: p = o2 . Wout + bout (fp32 exact) ----------------
__device__ __forceinline__ void head_do(int t, int r0, int step,
    const float* o2s, const float* WoutS, float bout0,
    float* __restrict__ out, float* pS)
{
  if (t < 256){
    int r = t >> 3, jj = t & 7;
    const float* orow = &o2s[r * 132 + jj * 16];
    const float* wrow = &WoutS[jj * 16];
    float s = 0.0f;
#pragma unroll
    for (int q = 0; q < 16; ++q) s += orow[q] * wrow[q];
    s += __shfl_down(s, 4, 8);
    s += __shfl_down(s, 2, 8);
    s += __shfl_down(s, 1, 8);
    if (jj == 0){
      float pv = s + bout0;
      out[(r0 + r) * T_STEPS + step] = pv;
      pS[r] = pv;
    }
  }
}

#define MFMA16 __builtin_amdgcn_mfma_f32_16x16x32_f16

// ---------------- main kernel ----------------
__global__ __launch_bounds__(512, 2)
void lstm_mfma(FeatPtrs fp, const float* __restrict__ irr,
               const _Float16* __restrict__ wsb,
               const float* __restrict__ bz, const float* __restrict__ b1,
               const float* __restrict__ b2, const float* __restrict__ Wout,
               const float* __restrict__ bout, float* __restrict__ out)
{
  // A-panels: [m-tile 0..1][16 rows][40 halfs] (k 0..31 data + 8 pad)
  __shared__ __align__(16) _Float16 xp[2][1280];    // x, double-buffered steps
  __shared__ __align__(16) _Float16 hp [4 * 1280];  // h, 4 ksteps
  __shared__ __align__(16) _Float16 o1p[4 * 1280];  // o1, 4 ksteps
  __shared__ __align__(16) float o2s[32 * 132];     // o2 fp32, padded rows
  __shared__ float WoutS[128];
  __shared__ float pS[32];

  const int t   = threadIdx.x;
  const int l   = t & 63;
  const int w   = t >> 6;        // wave 0..7, owns cols [16w,16w+16)
  const int c16 = l & 15;
  const int kq  = l >> 4;        // 0..3
  const int r0  = blockIdx.x * 32;

  // weight fragments -> registers (112 VGPRs, same footprint as r7)
  h8 Bz[4][5], B1f[4], B2f[4];
  {
    const h8* f8 = (const h8*)wsb;
#pragma unroll
    for (int g = 0; g < 4; ++g)
#pragma unroll
      for (int ks = 0; ks < 5; ++ks)
        Bz[g][ks] = f8[((w * 4 + g) * 5 + ks) * 64 + l];
#pragma unroll
    for (int ks = 0; ks < 4; ++ks) B1f[ks] = f8[(160 + w * 4 + ks) * 64 + l];
#pragma unroll
    for (int ks = 0; ks < 4; ++ks) B2f[ks] = f8[(192 + w * 4 + ks) * 64 + l];
  }
  float bzv[4], wi7[4];
#pragma unroll
  for (int g = 0; g < 4; ++g){
    bzv[g] = bz[g * 128 + w * 16 + c16];
    // Wi[7][col] as the SAME fp16 value the x-MFMA would use (frag elem kk=7)
    wi7[g] = (float)wsb[((w * 4 + g) * 5) * 512 + c16 * 8 + 7];
  }
  const float b1v   = b1[w * 16 + c16];
  const float b2v   = b2[w * 16 + c16];
  const float bout0 = bout[0];
  if (t < 128) WoutS[t] = Wout[t];

  // per-thread gather bases (threads t<256 own one (row,feature) slot)
  const float* fbase = nullptr;   // feature array base (j<7)
  const float* ibase = nullptr;   // irradiance base (j==7)
  int xslot = 0;
  if (t < 256){
    int r = t >> 3, j = t & 7;
    if (j < 7) fbase = fp.f[j] + (r0 + r) * T_STEPS;
    else       ibase = irr + (r0 + r) * WARM_N;
    xslot = (r >> 4) * 640 + (r & 15) * 40 + j;
  }

  { // zero x buffers (k8..31 must stay 0) and h panels (h0 = 0)
    int* p = (int*)xp;
    for (int i = t; i < 1280; i += 512) p[i] = 0;
    p = (int*)hp;
    for (int i = t; i < 2560; i += 512) p[i] = 0;
  }

  float cst[8];
#pragma unroll
  for (int i = 0; i < 8; ++i) cst[i] = 0.0f;

  const int aoff = c16 * 40 + kq * 8;                    // A-frag read offset
  const int wb   = (w >> 1) * 1280 + (w & 1) * 16 + c16; // h/o1 write base
  __syncthreads();

  // prologue: direct gathers for steps 0 and 1
  if (t < 256){
    float v0 = fbase ? fbase[0] : ibase[0];
    float v1 = fbase ? fbase[1] : ibase[1];
    xp[0][xslot] = (_Float16)v0;
    xp[1][xslot] = (_Float16)v1;
  }
  __syncthreads();

  // =================== pipelined warm loop: i = 0..22 ===================
  for (int i = 0; i < 23; ++i){
    // ---------------- PHASE A ----------------
    // issue gather loads for step i+2 (fire-and-forget; written in phase B)
    float vnext = 0.0f;
    if (t < 256){
      int step = i + 2;                       // 2..24
      if (fbase)               vnext = fbase[step];
      else if (step < WARM_N)  vnext = ibase[step];
      // step 24, j==7: stays 0 (p injected in tail)
    }
    // z(i) + MLP1(i-1), fused on shared h-panel reads
    float4v acc[4][2];
#pragma unroll
    for (int g = 0; g < 4; ++g)
#pragma unroll
      for (int m = 0; m < 2; ++m)
#pragma unroll
        for (int r = 0; r < 4; ++r) acc[g][m][r] = bzv[g];
    float4v m1[2];
#pragma unroll
    for (int m = 0; m < 2; ++m)
#pragma unroll
      for (int r = 0; r < 4; ++r) m1[m][r] = b1v;
    {
      const _Float16* xb = xp[i & 1];
      h8 a0 = *(const h8*)&xb[aoff];
      h8 a1 = *(const h8*)&xb[640 + aoff];
#pragma unroll
      for (int g = 0; g < 4; ++g){
        acc[g][0] = MFMA16(a0, Bz[g][0], acc[g][0], 0, 0, 0);
        acc[g][1] = MFMA16(a1, Bz[g][0], acc[g][1], 0, 0, 0);
      }
    }
#pragma unroll
    for (int ks = 0; ks < 4; ++ks){
      h8 ah0 = *(const h8*)&hp[ks * 1280 + aoff];
      h8 ah1 = *(const h8*)&hp[ks * 1280 + 640 + aoff];
#pragma unroll
      for (int g = 0; g < 4; ++g){
        acc[g][0] = MFMA16(ah0, Bz[g][1 + ks], acc[g][0], 0, 0, 0);
        acc[g][1] = MFMA16(ah1, Bz[g][1 + ks], acc[g][1], 0, 0, 0);
      }
      if (i >= 1){
        m1[0] = MFMA16(ah0, B1f[ks], m1[0], 0, 0, 0);
        m1[1] = MFMA16(ah1, B1f[ks], m1[1], 0, 0, 0);
      }
    }
    if (i >= 1){ // write o1p(i-1)
#pragma unroll
      for (int m = 0; m < 2; ++m)
#pragma unroll
        for (int r = 0; r < 4; ++r)
          o1p[wb + m * 640 + (kq * 4 + r) * 40] = (_Float16)fmaxf(m1[m][r], 0.0f);
    }
    if (i >= 2) head_do(t, r0, i - 2, o2s, WoutS, bout0, out, pS);
    __syncthreads();

    // ---------------- PHASE B ----------------
    // write staged gather (xp[i&1]'s reads completed at the barrier;
    // vmcnt for vnext resolved during phase A's MFMAs)
    if (t < 256) xp[i & 1][xslot] = (_Float16)vnext;
    // gates(i): acc -> c,h; write h panels (single fp16)
#pragma unroll
    for (int m = 0; m < 2; ++m)
#pragma unroll
      for (int r = 0; r < 4; ++r){
        float zi = acc[0][m][r], zf = acc[1][m][r], zg = acc[2][m][r], zo = acc[3][m][r];
        float c2 = sigm(zf) * cst[m * 4 + r] + sigm(zi) * tanh_(zg);
        cst[m * 4 + r] = c2;
        float h2 = sigm(zo) * tanh_(c2);
        hp[wb + m * 640 + (kq * 4 + r) * 40] = (_Float16)h2;  // row = kq*4+r
      }
    if (i >= 1){ // MLP2(i-1): o1p -> o2s
      float4v m2[2];
#pragma unroll
      for (int m = 0; m < 2; ++m)
#pragma unroll
        for (int r = 0; r < 4; ++r) m2[m][r] = b2v;
#pragma unroll
      for (int ks = 0; ks < 4; ++ks){
        h8 a0 = *(const h8*)&o1p[ks * 1280 + aoff];
        h8 a1 = *(const h8*)&o1p[ks * 1280 + 640 + aoff];
        m2[0] = MFMA16(a0, B2f[ks], m2[0], 0, 0, 0);
        m2[1] = MFMA16(a1, B2f[ks], m2[1], 0, 0, 0);
      }
#pragma unroll
      for (int m = 0; m < 2; ++m)
#pragma unroll
        for (int r = 0; r < 4; ++r)
          o2s[(m * 16 + kq * 4 + r) * 132 + w * 16 + c16] = fmaxf(m2[m][r], 0.0f);
    }
    __syncthreads();
  }

  // ============ P0: head(21) (o2s(21) written in warm i=22 phase B) ========
  head_do(t, r0, 21, o2s, WoutS, bout0, out, pS);
  __syncthreads();

  // ===== pipelined tail: s = 23..29, MLP(s-1) trails z(s), 4 barriers ======
  // xp[s&1] holds x(s): s=23 from warm B(21); s>=24 from TD(s-2). j7 slot is 0
  // for s>=24 (p injected in TD); loads for s+2 issued in TA, written in TD.
  for (int s = 23; s < T_STEPS; ++s){
    // ---- TA: issue gather(s+2) | z(s) + MLP1(s-1) ----
    float vnext = 0.0f;
    if (s <= 27 && t < 256 && fbase) vnext = fbase[s + 2];   // j==7 stays 0
    float4v acc[4][2];
#pragma unroll
    for (int g = 0; g < 4; ++g)
#pragma unroll
      for (int m = 0; m < 2; ++m)
#pragma unroll
        for (int r = 0; r < 4; ++r) acc[g][m][r] = bzv[g];
    float4v m1[2];
#pragma unroll
    for (int m = 0; m < 2; ++m)
#pragma unroll
      for (int r = 0; r < 4; ++r) m1[m][r] = b1v;
    {
      const _Float16* xb = xp[s & 1];   // s=23: j7=irr[23] (real); s>23: j7=0
      h8 a0 = *(const h8*)&xb[aoff];
      h8 a1 = *(const h8*)&xb[640 + aoff];
#pragma unroll
      for (int g = 0; g < 4; ++g){
        acc[g][0] = MFMA16(a0, Bz[g][0], acc[g][0], 0, 0, 0);
        acc[g][1] = MFMA16(a1, Bz[g][0], acc[g][1], 0, 0, 0);
      }
    }
#pragma unroll
    for (int ks = 0; ks < 4; ++ks){
      h8 ah0 = *(const h8*)&hp[ks * 1280 + aoff];
      h8 ah1 = *(const h8*)&hp[ks * 1280 + 640 + aoff];
#pragma unroll
      for (int g = 0; g < 4; ++g){
        acc[g][0] = MFMA16(ah0, Bz[g][1 + ks], acc[g][0], 0, 0, 0);
        acc[g][1] = MFMA16(ah1, Bz[g][1 + ks], acc[g][1], 0, 0, 0);
      }
      m1[0] = MFMA16(ah0, B1f[ks], m1[0], 0, 0, 0);
      m1[1] = MFMA16(ah1, B1f[ks], m1[1], 0, 0, 0);
    }
#pragma unroll
    for (int m = 0; m < 2; ++m)
#pragma unroll
      for (int r = 0; r < 4; ++r)
        o1p[wb + m * 640 + (kq * 4 + r) * 40] = (_Float16)fmaxf(m1[m][r], 0.0f);
    __syncthreads();

    // ---- TB: MLP2(s-1) ----
    {
      float4v m2[2];
#pragma unroll
      for (int m = 0; m < 2; ++m)
#pragma unroll
        for (int r = 0; r < 4; ++r) m2[m][r] = b2v;
#pragma unroll
      for (int ks = 0; ks < 4; ++ks){
        h8 a0 = *(const h8*)&o1p[ks * 1280 + aoff];
        h8 a1 = *(const h8*)&o1p[ks * 1280 + 640 + aoff];
        m2[0] = MFMA16(a0, B2f[ks], m2[0], 0, 0, 0);
        m2[1] = MFMA16(a1, B2f[ks], m2[1], 0, 0, 0);
      }
#pragma unroll
      for (int m = 0; m < 2; ++m)
#pragma unroll
        for (int r = 0; r < 4; ++r)
          o2s[(m * 16 + kq * 4 + r) * 132 + w * 16 + c16] = fmaxf(m2[m][r], 0.0f);
    }
    __syncthreads();

    // ---- TC: head(s-1) -> out, pS ----
    head_do(t, r0, s - 1, o2s, WoutS, bout0, out, pS);
    __syncthreads();

    // ---- TD: write staged gather | p-inject (s>=24) + gates(s) -> hp ----
    if (s <= 27 && t < 256) xp[s & 1][xslot] = (_Float16)vnext;
    if (s >= 24){
#pragma unroll
      for (int m = 0; m < 2; ++m)
#pragma unroll
        for (int r = 0; r < 4; ++r){
          float pv = pS[m * 16 + kq * 4 + r];
#pragma unroll
          for (int g = 0; g < 4; ++g) acc[g][m][r] += pv * wi7[g];
        }
    }
#pragma unroll
    for (int m = 0; m < 2; ++m)
#pragma unroll
      for (int r = 0; r < 4; ++r){
        float zi = acc[0][m][r], zf = acc[1][m][r], zg = acc[2][m][r], zo = acc[3][m][r];
        float c2 = sigm(zf) * cst[m * 4 + r] + sigm(zi) * tanh_(zg);
        cst[m * 4 + r] = c2;
        float h2 = sigm(zo) * tanh_(c2);
        hp[wb + m * 640 + (kq * 4 + r) * 40] = (_Float16)h2;
      }
    __syncthreads();
  }

  // =================== final drain: MLP1(29) | MLP2(29) | head(29) =========
  {
    float4v m1[2];
#pragma unroll
    for (int m = 0; m < 2; ++m)
#pragma unroll
      for (int r = 0; r < 4; ++r) m1[m][r] = b1v;
#pragma unroll
    for (int ks = 0; ks < 4; ++ks){
      h8 ah0 = *(const h8*)&hp[ks * 1280 + aoff];
      h8 ah1 = *(const h8*)&hp[ks * 1280 + 640 + aoff];
      m1[0] = MFMA16(ah0, B1f[ks], m1[0], 0, 0, 0);
      m1[1] = MFMA16(ah1, B1f[ks], m1[1], 0, 0, 0);
    }
#pragma unroll
    for (int m = 0; m < 2; ++m)
#pragma unroll
      for (int r = 0; r < 4; ++r)
        o1p[wb + m * 640 + (kq * 4 + r) * 40] = (_Float16)fmaxf(m1[m][r], 0.0f);
    __syncthreads();
    float4v m2[2];
#pragma unroll
    for (int m = 0; m < 2; ++m)
#pragma unroll
      for (int r = 0; r < 4; ++r) m2[m][r] = b2v;
#pragma unroll
    for (int ks = 0; ks < 4; ++ks){
      h8 a0 = *(const h8*)&o1p[ks * 1280 + aoff];
      h8 a1 = *(const h8*)&o1p[ks * 1280 + 640 + aoff];
      m2[0] = MFMA16(a0, B2f[ks], m2[0], 0, 0, 0);
      m2[1] = MFMA16(a1, B2f[ks], m2[1], 0, 0, 0);
    }
#pragma unroll
    for (int m = 0; m < 2; ++m)
#pragma unroll
      for (int r = 0; r < 4; ++r)
        o2s[(m * 16 + kq * 4 + r) * 132 + w * 16 + c16] = fmaxf(m2[m][r], 0.0f);
    __syncthreads();
    head_do(t, r0, 29, o2s, WoutS, bout0, out, pS);
  }
}

extern "C" void kernel_launch(void* const* d_in, const int* in_sizes, int n_in,
                              void* d_out, int out_size, void* d_ws, size_t ws_size,
                              hipStream_t stream)
{
  (void)in_sizes; (void)n_in; (void)out_size; (void)ws_size;
  // inputs: 0..7 weather (unused), 8..14 time feats, 15 irradiance_in,
  // 16 Wi, 17 Wh, 18 b, 19 W1, 20 b1, 21 W2, 22 b2, 23 Wout, 24 bout
  FeatPtrs fp;
  for (int j = 0; j < 7; ++j) fp.f[j] = (const float*)d_in[8 + j];
  const float* irr  = (const float*)d_in[15];
  const float* Wi   = (const float*)d_in[16];
  const float* Wh   = (const float*)d_in[17];
  const float* bz   = (const float*)d_in[18];
  const float* W1   = (const float*)d_in[19];
  const float* b1   = (const float*)d_in[20];
  const float* W2   = (const float*)d_in[21];
  const float* b2   = (const float*)d_in[22];
  const float* Wout = (const float*)d_in[23];
  const float* bout = (const float*)d_in[24];

  _Float16* ws = (_Float16*)d_ws;                 // 224*512*2 = 224 KB used
  pack_weights<<<dim3(448), dim3(256), 0, stream>>>(Wi, Wh, W1, W2, ws);
  lstm_mfma<<<dim3(256), dim3(512), 0, stream>>>(
      fp, irr, ws, bz, b1, b2, Wout, bout, (float*)d_out);
}